// Round 2
// baseline (282.380 us; speedup 1.0000x reference)
//
#include <hip/hip_runtime.h>

typedef __attribute__((ext_vector_type(8))) short short8;
typedef __attribute__((ext_vector_type(4))) float f32x4;

__device__ __forceinline__ unsigned short f32_to_bf16(float f) {
    union { float f; unsigned int u; } c; c.f = f;
    unsigned int u = c.u;
    unsigned int r = (u + 0x7fffu + ((u >> 16) & 1u)) >> 16;  // RNE
    return (unsigned short)r;
}

// Fused: normalize rows of inputs [nA,128] and kernel [nB,128] fp32 ->
// bf16 rows scaled 3/||v||, plus sq-norm out. One wave per row.
__global__ void norm_kernel(const float* __restrict__ inA, int nA,
                            const float* __restrict__ inB,
                            unsigned short* __restrict__ xA,
                            unsigned short* __restrict__ pB,
                            float* __restrict__ xs,
                            float* __restrict__ ps) {
    const int row  = blockIdx.x * 4 + (threadIdx.x >> 6);
    const int lane = threadIdx.x & 63;
    const float* src;
    unsigned short* dst;
    float* sdst;
    if (row < nA) {
        src = inA + (size_t)row * 128; dst = xA + (size_t)row * 128; sdst = xs + row;
    } else {
        const int r2 = row - nA;
        src = inB + (size_t)r2 * 128; dst = pB + (size_t)r2 * 128; sdst = ps + r2;
    }
    const float2 v = ((const float2*)src)[lane];
    float s = fmaf(v.x, v.x, v.y * v.y);
#pragma unroll
    for (int off = 32; off; off >>= 1) s += __shfl_xor(s, off, 64);
    const float r  = rsqrtf(fmaxf(s, 1e-12f));
    const float sc = 3.0f * r;
    ushort2 o;
    o.x = f32_to_bf16(v.x * sc);
    o.y = f32_to_bf16(v.y * sc);
    ((ushort2*)dst)[lane] = o;
    if (lane == 0) *sdst = 9.0f * s * (r * r);
}

// out = xs[b] + ps[c] - 2 * A*B^T. A:[M,128] bf16, B:[N,128] bf16, row-major.
// 128x128 tile/block, full K=128 staged once via global_load_lds (16B lanes,
// lane-linear LDS dest; 16B chunks XOR-swizzled within rows so fragment
// ds_read_b128s are <=2-way bank-aliased, which is free on CDNA4).
// MFMA operands are SWAPPED (bf as A-operand): D layout col=lane&15 ->
// out-ROW, row=quad*4+reg -> out-COL, so each lane owns 4 consecutive
// output columns => dwordx4 stores (16 per thread vs 64 dword stores).
__global__ __launch_bounds__(256, 2) void gemm_kernel(
    const unsigned short* __restrict__ A,
    const unsigned short* __restrict__ B,
    const float* __restrict__ xs,
    const float* __restrict__ ps,
    float* __restrict__ out,
    int Ncols)
{
    __shared__ unsigned short sA[128 * 128];  // 32 KB
    __shared__ unsigned short sB[128 * 128];  // 32 KB

    const int tid  = threadIdx.x;
    const int lane = tid & 63;
    const int wave = tid >> 6;
    const int bm   = blockIdx.y;
    const int bn   = blockIdx.x;

    const int wm   = (wave >> 1) * 64;
    const int wn   = (wave & 1) * 64;
    const int l15  = lane & 15;
    const int quad = lane >> 4;

    // Epilogue scalars in registers (LDS stays exactly 64 KB).
    // Swapped layout: lane's out rows = wm+mt*16+l15; cols = wn+nt*16+quad*4+r.
    float xsr[4];
#pragma unroll
    for (int mt = 0; mt < 4; ++mt)
        xsr[mt] = xs[bm * 128 + wm + mt * 16 + l15];
    float psr[16];
#pragma unroll
    for (int nt = 0; nt < 4; ++nt)
#pragma unroll
        for (int r = 0; r < 4; ++r)
            psr[nt * 4 + r] = ps[bn * 128 + wn + nt * 16 + quad * 4 + r];

    // --- stage A and B tiles: 2048 x 16B chunks each
    {
        const char* gA = (const char*)(A + (size_t)bm * 128 * 128);
        const char* gB = (const char*)(B + (size_t)bn * 128 * 128);
#pragma unroll
        for (int it = 0; it < 8; ++it) {
            const int cid = it * 256 + wave * 64 + lane;
            const int m   = cid >> 4;
            const int jj  = cid & 15;
            const int gj  = jj ^ (m & 7);
            const int gbyte = m * 256 + gj * 16;
            const int lbyte = cid * 16;
            __builtin_amdgcn_global_load_lds(
                (const __attribute__((address_space(1))) void*)(gA + gbyte),
                (__attribute__((address_space(3))) void*)((char*)sA + lbyte),
                16, 0, 0);
            __builtin_amdgcn_global_load_lds(
                (const __attribute__((address_space(1))) void*)(gB + gbyte),
                (__attribute__((address_space(3))) void*)((char*)sB + lbyte),
                16, 0, 0);
        }
    }
    __syncthreads();

    f32x4 acc[4][4];
#pragma unroll
    for (int i = 0; i < 4; ++i)
#pragma unroll
        for (int j = 0; j < 4; ++j)
            acc[i][j] = (f32x4){0.f, 0.f, 0.f, 0.f};

#pragma unroll
    for (int kk = 0; kk < 4; ++kk) {
        short8 af[4], bfv[4];
#pragma unroll
        for (int mt = 0; mt < 4; ++mt) {
            const int m  = wm + mt * 16 + l15;
            const int jj = (kk * 4 + quad) ^ (m & 7);
            af[mt] = *(const short8*)&sA[m * 128 + jj * 8];
        }
#pragma unroll
        for (int nt = 0; nt < 4; ++nt) {
            const int n  = wn + nt * 16 + l15;
            const int jj = (kk * 4 + quad) ^ (n & 7);
            bfv[nt] = *(const short8*)&sB[n * 128 + jj * 8];
        }
        // swapped operands: B-fragment in the A slot
#pragma unroll
        for (int mt = 0; mt < 4; ++mt)
#pragma unroll
            for (int nt = 0; nt < 4; ++nt)
                acc[mt][nt] = __builtin_amdgcn_mfma_f32_16x16x32_bf16(
                    bfv[nt], af[mt], acc[mt][nt], 0, 0, 0);
    }

    // --- epilogue: out = xs[b] + ps[c] - 2*dot, float4 stores
    const size_t stride = (size_t)Ncols;
#pragma unroll
    for (int mt = 0; mt < 4; ++mt) {
        const int grow = bm * 128 + wm + mt * 16 + l15;
        float* rowp = out + (size_t)grow * stride + bn * 128 + wn + quad * 4;
#pragma unroll
        for (int nt = 0; nt < 4; ++nt) {
            f32x4 v;
#pragma unroll
            for (int r = 0; r < 4; ++r)
                v[r] = fmaf(-2.0f, acc[mt][nt][r], xsr[mt] + psr[nt * 4 + r]);
            *(f32x4*)(rowp + nt * 16) = v;
        }
    }
}

extern "C" void kernel_launch(void* const* d_in, const int* in_sizes, int n_in,
                              void* d_out, int out_size, void* d_ws, size_t ws_size,
                              hipStream_t stream) {
    const float* inputs = (const float*)d_in[0];
    const float* kern   = (const float*)d_in[1];
    float* out          = (float*)d_out;

    const int D = 128;
    const int B = in_sizes[0] / D;   // 4096
    const int C = in_sizes[1] / D;   // 16384

    char* ws = (char*)d_ws;
    unsigned short* xA = (unsigned short*)ws;                       // B*D bf16
    unsigned short* pB = (unsigned short*)(ws + (size_t)B * D * 2); // C*D bf16
    float* xs = (float*)(ws + (size_t)(B + C) * D * 2);             // B floats
    float* ps = xs + B;                                             // C floats

    norm_kernel<<<(B + C) / 4, 256, 0, stream>>>(inputs, B, kern, xA, pB, xs, ps);

    dim3 grid(C / 128, B / 128);  // 128 x 32 = 4096 blocks
    gemm_kernel<<<grid, 256, 0, stream>>>(xA, pB, xs, ps, out, C);
}